// Round 1
// baseline (28950.748 us; speedup 1.0000x reference)
//
#include <hip/hip_runtime.h>
#include <math.h>

// Problem constants (match reference)
#define BDIM 256
#define DDIM 2048
constexpr float DT    = 0.1f;
constexpr float TOL   = 0.01f;
constexpr int   NSTEP = 50;      // int(5.0 / 0.1)
constexpr float EPS_  = 1e-8f;

// GEMM tiling
constexpr int BM = 32, BN = 64, BK = 32;
constexpr int TM = 2,  TN = 4;   // 256 threads -> 32x64 tile

static_assert(BDIM % BM == 0 && DDIM % BN == 0 && DDIM % BK == 0, "tiling");

// ---------------------------------------------------------------------------
// GEMM1 (NN) fused: h = tanh((xb + c*kp) @ W + bias)
// A = xb (+ c*kp) computed on the fly, so RK4 stage inputs are never stored.
// ---------------------------------------------------------------------------
template<bool FUSE>
__global__ __launch_bounds__(256)
void gemm_tanh_k(const float* __restrict__ xb, const float* __restrict__ kp, float c,
                 const float* __restrict__ W, const float* __restrict__ bias,
                 float* __restrict__ hout, const int* __restrict__ done)
{
    if (*done) return;
    __shared__ float As[BK][BM + 2];   // transposed A tile, padded (stride 34: 8B-aligned b64 reads)
    __shared__ float Bs[BK][BN + 4];   // padded (stride 68: 16B-aligned b128 reads)

    const int t    = threadIdx.x;
    const int bn   = blockIdx.x, bm = blockIdx.y;
    const int row0 = bm * BM,    col0 = bn * BN;
    const int tx   = t & 15,     ty   = t >> 4;
    const int ar   = t >> 3,     ac   = (t & 7) << 2;   // A: 32 rows x (8 thr * float4)
    const int br   = t >> 4,     bc   = (t & 15) << 2;  // B: rows br, br+16; 64 cols

    const float* aPtr  = xb + (size_t)(row0 + ar) * DDIM + ac;
    const float* kPtr  = FUSE ? (kp + (size_t)(row0 + ar) * DDIM + ac) : nullptr;
    const float* bPtr0 = W + (size_t)br * DDIM + col0 + bc;
    const float* bPtr1 = W + (size_t)(br + 16) * DDIM + col0 + bc;

    float4 aReg, kReg, bReg0, bReg1;
    auto gload = [&](int kt) {
        aReg  = *(const float4*)(aPtr + kt);
        if (FUSE) kReg = *(const float4*)(kPtr + kt);
        bReg0 = *(const float4*)(bPtr0 + (size_t)kt * DDIM);
        bReg1 = *(const float4*)(bPtr1 + (size_t)kt * DDIM);
    };
    auto sstore = [&]() {
        float4 v = aReg;
        if (FUSE) { v.x += c*kReg.x; v.y += c*kReg.y; v.z += c*kReg.z; v.w += c*kReg.w; }
        As[ac+0][ar] = v.x; As[ac+1][ar] = v.y; As[ac+2][ar] = v.z; As[ac+3][ar] = v.w;
        *(float4*)&Bs[br][bc]      = bReg0;
        *(float4*)&Bs[br+16][bc]   = bReg1;
    };

    float acc[TM][TN] = {};
    gload(0);
    sstore();
    for (int kt = 0; kt < DDIM; kt += BK) {
        __syncthreads();
        const bool more = (kt + BK) < DDIM;
        if (more) gload(kt + BK);   // register-staged prefetch; latency hides under compute
        #pragma unroll
        for (int kk = 0; kk < BK; ++kk) {
            const float2 av = *(const float2*)&As[kk][ty * TM];
            const float4 bv = *(const float4*)&Bs[kk][tx * TN];
            acc[0][0] += av.x * bv.x; acc[0][1] += av.x * bv.y;
            acc[0][2] += av.x * bv.z; acc[0][3] += av.x * bv.w;
            acc[1][0] += av.y * bv.x; acc[1][1] += av.y * bv.y;
            acc[1][2] += av.y * bv.z; acc[1][3] += av.y * bv.w;
        }
        __syncthreads();
        if (more) sstore();
    }

    const float4 bb = *(const float4*)&bias[col0 + tx * TN];
    #pragma unroll
    for (int m = 0; m < TM; ++m) {
        const int row = row0 + ty * TM + m;
        float4 o;
        o.x = tanhf(acc[m][0] + bb.x);
        o.y = tanhf(acc[m][1] + bb.y);
        o.z = tanhf(acc[m][2] + bb.z);
        o.w = tanhf(acc[m][3] + bb.w);
        *(float4*)&hout[(size_t)row * DDIM + col0 + tx * TN] = o;
    }
}

// ---------------------------------------------------------------------------
// GEMM2 (NT) fused: kout = -(coef[i] * h * (1-h^2)) @ W^T
// Optionally accumulates global max|kout| via atomicMax (for the stop cond).
// ---------------------------------------------------------------------------
template<bool DOMAX>
__global__ __launch_bounds__(256)
void gemm_nt_k(const float* __restrict__ h, const float* __restrict__ coef,
               const float* __restrict__ W, float* __restrict__ kout,
               unsigned* __restrict__ maxu, const int* __restrict__ done)
{
    if (*done) return;
    __shared__ float As[BK][BM + 2];
    __shared__ float Bs[BK][BN + 4];

    const int t    = threadIdx.x;
    const int bn   = blockIdx.x, bm = blockIdx.y;
    const int row0 = bm * BM,    col0 = bn * BN;
    const int tx   = t & 15,     ty   = t >> 4;
    const int ar   = t >> 3,     ac   = (t & 7) << 2;
    const int bj   = t >> 3,     bk   = (t & 7) << 2;   // B tile: 64 W-rows x 32 k

    const float cf     = coef[row0 + ar];
    const float* aPtr  = h + (size_t)(row0 + ar) * DDIM + ac;
    const float* bPtr0 = W + (size_t)(col0 + bj) * DDIM + bk;
    const float* bPtr1 = W + (size_t)(col0 + bj + 32) * DDIM + bk;

    float4 aReg, bReg0, bReg1;
    auto gload = [&](int kt) {
        aReg  = *(const float4*)(aPtr + kt);
        bReg0 = *(const float4*)(bPtr0 + kt);
        bReg1 = *(const float4*)(bPtr1 + kt);
    };
    auto sstore = [&]() {
        // g = coef * h * (1 - h^2), computed at LDS-store time
        const float g0 = cf * aReg.x * (1.f - aReg.x * aReg.x);
        const float g1 = cf * aReg.y * (1.f - aReg.y * aReg.y);
        const float g2 = cf * aReg.z * (1.f - aReg.z * aReg.z);
        const float g3 = cf * aReg.w * (1.f - aReg.w * aReg.w);
        As[ac+0][ar] = g0; As[ac+1][ar] = g1; As[ac+2][ar] = g2; As[ac+3][ar] = g3;
        Bs[bk+0][bj]    = bReg0.x; Bs[bk+1][bj]    = bReg0.y;
        Bs[bk+2][bj]    = bReg0.z; Bs[bk+3][bj]    = bReg0.w;
        Bs[bk+0][bj+32] = bReg1.x; Bs[bk+1][bj+32] = bReg1.y;
        Bs[bk+2][bj+32] = bReg1.z; Bs[bk+3][bj+32] = bReg1.w;
    };

    float acc[TM][TN] = {};
    gload(0);
    sstore();
    for (int kt = 0; kt < DDIM; kt += BK) {
        __syncthreads();
        const bool more = (kt + BK) < DDIM;
        if (more) gload(kt + BK);
        #pragma unroll
        for (int kk = 0; kk < BK; ++kk) {
            const float2 av = *(const float2*)&As[kk][ty * TM];
            const float4 bv = *(const float4*)&Bs[kk][tx * TN];
            acc[0][0] += av.x * bv.x; acc[0][1] += av.x * bv.y;
            acc[0][2] += av.x * bv.z; acc[0][3] += av.x * bv.w;
            acc[1][0] += av.y * bv.x; acc[1][1] += av.y * bv.y;
            acc[1][2] += av.y * bv.z; acc[1][3] += av.y * bv.w;
        }
        __syncthreads();
        if (more) sstore();
    }

    float mx = 0.f;
    #pragma unroll
    for (int m = 0; m < TM; ++m) {
        const int row = row0 + ty * TM + m;
        float4 o;
        o.x = -acc[m][0]; o.y = -acc[m][1]; o.z = -acc[m][2]; o.w = -acc[m][3];
        *(float4*)&kout[(size_t)row * DDIM + col0 + tx * TN] = o;
        if (DOMAX) {
            mx = fmaxf(mx, fmaxf(fmaxf(fabsf(o.x), fabsf(o.y)), fmaxf(fabsf(o.z), fabsf(o.w))));
        }
    }
    if (DOMAX) {
        #pragma unroll
        for (int off = 32; off; off >>= 1) mx = fmaxf(mx, __shfl_xor(mx, off));
        if ((t & 63) == 0) atomicMax(maxu, __float_as_uint(mx));  // nonneg float bits: monotone
    }
}

// ---------------------------------------------------------------------------
// coef[r] = 5 / (sqrt(sum_j h[r,j]^2) + 1e-8)
// ---------------------------------------------------------------------------
__global__ __launch_bounds__(256)
void rowcoef_k(const float* __restrict__ h, float* __restrict__ coef,
               const int* __restrict__ done)
{
    if (*done) return;
    const int r = blockIdx.x;
    const float* p = h + (size_t)r * DDIM;
    float s = 0.f;
    for (int j = threadIdx.x * 4; j < DDIM; j += 256 * 4) {
        const float4 v = *(const float4*)&p[j];
        s += v.x*v.x + v.y*v.y + v.z*v.z + v.w*v.w;
    }
    #pragma unroll
    for (int off = 32; off; off >>= 1) s += __shfl_xor(s, off);
    __shared__ float wsum[4];
    if ((threadIdx.x & 63) == 0) wsum[threadIdx.x >> 6] = s;
    __syncthreads();
    if (threadIdx.x == 0) {
        const float tot = wsum[0] + wsum[1] + wsum[2] + wsum[3];
        coef[r] = 5.0f / (sqrtf(tot) + EPS_);
    }
}

// done |= (max|k1| < TOL); reset the max accumulator for the next step
__global__ void finalize_k(unsigned* __restrict__ maxu, int* __restrict__ done)
{
    if (!*done) {
        if (__uint_as_float(*maxu) < TOL) *done = 1;
    }
    *maxu = 0u;
}

__global__ __launch_bounds__(256)
void update_k(float* __restrict__ x, const float* __restrict__ k1,
              const float* __restrict__ k2, const float* __restrict__ k3,
              const float* __restrict__ k4, const int* __restrict__ done)
{
    if (*done) return;
    const size_t i = ((size_t)blockIdx.x * 256 + threadIdx.x) * 4;
    float4 xv = *(const float4*)&x[i];
    const float4 a = *(const float4*)&k1[i];
    const float4 b = *(const float4*)&k2[i];
    const float4 c = *(const float4*)&k3[i];
    const float4 d = *(const float4*)&k4[i];
    const float s = DT / 6.0f;
    xv.x += s * (a.x + 2.f*b.x + 2.f*c.x + d.x);
    xv.y += s * (a.y + 2.f*b.y + 2.f*c.y + d.y);
    xv.z += s * (a.z + 2.f*b.z + 2.f*c.z + d.z);
    xv.w += s * (a.w + 2.f*b.w + 2.f*c.w + d.w);
    *(float4*)&x[i] = xv;
}

__global__ __launch_bounds__(256)
void init_k(const float* __restrict__ x0, float* __restrict__ x,
            unsigned* __restrict__ maxu, int* __restrict__ done)
{
    const size_t i = ((size_t)blockIdx.x * 256 + threadIdx.x) * 4;
    *(float4*)&x[i] = *(const float4*)&x0[i];
    if (blockIdx.x == 0 && threadIdx.x == 0) { *maxu = 0u; *done = 0; }
}

__global__ __launch_bounds__(256)
void copy_k(const float* __restrict__ src, float* __restrict__ dst)
{
    const size_t i = ((size_t)blockIdx.x * 256 + threadIdx.x) * 4;
    *(float4*)&dst[i] = *(const float4*)&src[i];
}

// ---------------------------------------------------------------------------
extern "C" void kernel_launch(void* const* d_in, const int* in_sizes, int n_in,
                              void* d_out, int out_size, void* d_ws, size_t ws_size,
                              hipStream_t stream)
{
    const float* x0   = (const float*)d_in[0];
    const float* W    = (const float*)d_in[1];
    const float* bias = (const float*)d_in[2];
    float* out = (float*)d_out;

    const size_t NE = (size_t)BDIM * DDIM;  // 524288
    float* ws   = (float*)d_ws;
    float* x    = ws;
    float* h    = ws + NE;
    float* k1   = ws + 2 * NE;
    float* k2   = ws + 3 * NE;
    float* k3   = ws + 4 * NE;
    float* k4   = ws + 5 * NE;
    float* coef = ws + 6 * NE;
    unsigned* maxu = (unsigned*)(ws + 6 * NE + BDIM);
    int*      done = (int*)(ws + 6 * NE + BDIM + 1);

    const dim3 gG(DDIM / BN, BDIM / BM);   // (32, 8) = 256 blocks
    const int  gE = (int)(NE / 1024);      // 512 blocks of 256 thr, float4

    init_k<<<gE, 256, 0, stream>>>(x0, x, maxu, done);

    for (int s = 0; s < NSTEP; ++s) {
        // k1 = pvf(x); also feeds the stop condition
        gemm_tanh_k<false><<<gG, 256, 0, stream>>>(x, nullptr, 0.f, W, bias, h, done);
        rowcoef_k<<<BDIM, 256, 0, stream>>>(h, coef, done);
        gemm_nt_k<true><<<gG, 256, 0, stream>>>(h, coef, W, k1, maxu, done);
        finalize_k<<<1, 1, 0, stream>>>(maxu, done);
        // k2 = pvf(x + 0.5*DT*k1)
        gemm_tanh_k<true><<<gG, 256, 0, stream>>>(x, k1, 0.5f * DT, W, bias, h, done);
        rowcoef_k<<<BDIM, 256, 0, stream>>>(h, coef, done);
        gemm_nt_k<false><<<gG, 256, 0, stream>>>(h, coef, W, k2, nullptr, done);
        // k3 = pvf(x + 0.5*DT*k2)
        gemm_tanh_k<true><<<gG, 256, 0, stream>>>(x, k2, 0.5f * DT, W, bias, h, done);
        rowcoef_k<<<BDIM, 256, 0, stream>>>(h, coef, done);
        gemm_nt_k<false><<<gG, 256, 0, stream>>>(h, coef, W, k3, nullptr, done);
        // k4 = pvf(x + DT*k3)
        gemm_tanh_k<true><<<gG, 256, 0, stream>>>(x, k3, DT, W, bias, h, done);
        rowcoef_k<<<BDIM, 256, 0, stream>>>(h, coef, done);
        gemm_nt_k<false><<<gG, 256, 0, stream>>>(h, coef, W, k4, nullptr, done);
        // x += DT/6 * (k1 + 2k2 + 2k3 + k4)   (skipped if done)
        update_k<<<gE, 256, 0, stream>>>(x, k1, k2, k3, k4, done);
    }

    copy_k<<<gE, 256, 0, stream>>>(x, out);
}

// Round 2
// 14101.419 us; speedup vs baseline: 2.0530x; 2.0530x over previous
//
#include <hip/hip_runtime.h>
#include <math.h>

// Problem constants (match reference)
#define BDIM 256
#define DDIM 2048
constexpr float DT    = 0.1f;
constexpr float TOL   = 0.01f;
constexpr int   NSTEP = 50;      // int(5.0 / 0.1)
constexpr float EPS_  = 1e-8f;

typedef __attribute__((ext_vector_type(8))) short short8;   // 8 bf16 = 4 VGPR (MFMA A/B frag)
typedef __attribute__((ext_vector_type(4))) float f32x4;    // MFMA C/D frag

__device__ __forceinline__ ushort f2bf(float f) {           // fp32 -> bf16 RNE
    unsigned u = __float_as_uint(f);
    return (ushort)((u + 0x7fffu + ((u >> 16) & 1u)) >> 16);
}
__device__ __forceinline__ float bf2f(ushort h) { return __uint_as_float(((unsigned)h) << 16); }
__device__ __forceinline__ float4 ldf4(const float* p) { return *(const float4*)p; }

#define GLOAD_LDS16(g, l) __builtin_amdgcn_global_load_lds( \
    (const __attribute__((address_space(1))) void*)(g),      \
    (__attribute__((address_space(3))) void*)(l), 16, 0, 0)

// ===========================================================================
// NEW PATH: bf16 split-precision MFMA pipeline
// ===========================================================================

// One-time prepack: W -> bf16 hi/lo, row-major (for NT gemm: B[j][n]=W[j][n])
__global__ __launch_bounds__(256)
void prep_w_k(const float* __restrict__ W, ushort* __restrict__ Wh, ushort* __restrict__ Wl)
{
    const size_t i = ((size_t)blockIdx.x * 256 + threadIdx.x) * 4;
    const float4 v = *(const float4*)(W + i);
    ushort4 h, l;
    h.x = f2bf(v.x); l.x = f2bf(v.x - bf2f(h.x));
    h.y = f2bf(v.y); l.y = f2bf(v.y - bf2f(h.y));
    h.z = f2bf(v.z); l.z = f2bf(v.z - bf2f(h.z));
    h.w = f2bf(v.w); l.w = f2bf(v.w - bf2f(h.w));
    *(ushort4*)(Wh + i) = h;
    *(ushort4*)(Wl + i) = l;
}

// One-time prepack: W^T -> bf16 hi/lo (for NN gemm: B[k][n]=W[k][n] wants [n][k])
__global__ __launch_bounds__(256)
void prep_wt_k(const float* __restrict__ W, ushort* __restrict__ Wth, ushort* __restrict__ Wtl)
{
    __shared__ float T[64][65];
    const int t = threadIdx.x;
    const int k0 = blockIdx.y * 64, n0 = blockIdx.x * 64;
    const int r = t >> 2, c4 = (t & 3) * 16;
    const float* src = W + (size_t)(k0 + r) * DDIM + n0 + c4;
    #pragma unroll
    for (int j = 0; j < 4; ++j) {
        const float4 v = *(const float4*)(src + j * 4);
        T[r][c4 + j*4 + 0] = v.x; T[r][c4 + j*4 + 1] = v.y;
        T[r][c4 + j*4 + 2] = v.z; T[r][c4 + j*4 + 3] = v.w;
    }
    __syncthreads();
    ushort hb[16], lb[16];
    #pragma unroll
    for (int j = 0; j < 16; ++j) {
        const float v = T[c4 + j][r];           // Wt[n0+r][k0+c4+j] = W[k0+c4+j][n0+r]
        hb[j] = f2bf(v); lb[j] = f2bf(v - bf2f(hb[j]));
    }
    ushort* oh = Wth + (size_t)(n0 + r) * DDIM + k0 + c4;
    ushort* ol = Wtl + (size_t)(n0 + r) * DDIM + k0 + c4;
    #pragma unroll
    for (int q = 0; q < 4; ++q) {
        *(ushort4*)(oh + q*4) = make_ushort4(hb[q*4], hb[q*4+1], hb[q*4+2], hb[q*4+3]);
        *(ushort4*)(ol + q*4) = make_ushort4(lb[q*4], lb[q*4+1], lb[q*4+2], lb[q*4+3]);
    }
}

__global__ __launch_bounds__(256)
void init2_k(const float* __restrict__ x0, float* __restrict__ x,
             float* __restrict__ csum, unsigned* __restrict__ maxu, int* __restrict__ done)
{
    const size_t i = ((size_t)blockIdx.x * 256 + threadIdx.x) * 4;
    *(float4*)(x + i) = *(const float4*)(x0 + i);
    if (blockIdx.x == 0) {
        for (int j = threadIdx.x; j < 1024; j += 256) csum[j] = 0.f;
        if (threadIdx.x == 0) { *maxu = 0u; *done = 0; }
    }
}

// ---------------------------------------------------------------------------
// Fused split-bf16 MFMA GEMM. Tile 32x64, grid (32,8)=256 blocks, 256 thr.
// K split across wave pairs: waves {0,1} do K[0,1024), {2,3} K[1024,2048);
// LDS reduction at the end. Each wave: 2 m-frags x 2 n-frags of 16x16x32.
// 3-term split: hi*hi + hi*lo + lo*hi (err ~2^-18).
// MODE: 0=NN  h=tanh(x@W+b)               (+ row-sum(h^2) atomics into csum_cur)
//       1=NN fused A=(x+cmul*kp)
//       2=NT  k=-(cf*h*(1-h^2))@W^T       (cf = 5/(sqrt(csum_cur[row])+eps))
//       3=NT + global max|k| atomics
//       4=NT + RK4 x-update (x += DT/6*(k1+2k2+2k3+k4)), k4 not stored
// NT modes zero csum_next (block 0,0) for the following stage.
// ---------------------------------------------------------------------------
template<int MODE>
__global__ __launch_bounds__(256)
void hop_mm(const float* __restrict__ Asrc, const float* __restrict__ kp, float cmul,
            const ushort* __restrict__ Bhg, const ushort* __restrict__ Blg,
            const float* __restrict__ bias, float* __restrict__ outp,
            float* __restrict__ csum_cur, float* __restrict__ csum_next,
            const float* __restrict__ k1p, const float* __restrict__ k2p,
            const float* __restrict__ k3p, float* __restrict__ xbuf,
            unsigned* __restrict__ maxu, const int* __restrict__ done)
{
    constexpr bool NN    = (MODE <= 1);
    constexpr bool FUSE  = (MODE == 1);
    constexpr bool DOMAX = (MODE == 3);
    constexpr bool UPD   = (MODE == 4);
    if (*done) return;

    // [dbuf][K-half][row|col][k] bf16; 48 KB total
    __shared__ __align__(16) ushort Ah[2][2][32][32];
    __shared__ __align__(16) ushort Al[2][2][32][32];
    __shared__ __align__(16) ushort Bh[2][2][64][32];
    __shared__ __align__(16) ushort Bl[2][2][64][32];

    const int t = threadIdx.x, lane = t & 63, w = t >> 6;
    const int row0 = blockIdx.y * 32, col0 = blockIdx.x * 64;

    if (!NN && blockIdx.x == 0 && blockIdx.y == 0) csum_next[t] = 0.f;

    // ---- A staging: 256 thr x 8 fp32 -> bf16 hi/lo (one row each) ----
    const int sa_half = t >> 7, sa_tid = t & 127;
    const int sa_row = sa_tid >> 2, sa_kq = (sa_tid & 3) * 8;
    const float* aBase = Asrc + (size_t)(row0 + sa_row) * DDIM + sa_half * 1024 + sa_kq;
    const float* kBase = FUSE ? (kp + (size_t)(row0 + sa_row) * DDIM + sa_half * 1024 + sa_kq) : nullptr;
    float cf = 0.f;
    if (!NN) cf = 5.0f / (sqrtf(csum_cur[row0 + sa_row]) + EPS_);

    // ---- B staging: wave w handles (half=w>>1, hi/lo=w&1), 4 DMA/iter ----
    const int sb_half = w >> 1, sb_hl = w & 1;
    const int sb_cl = lane >> 2, sb_kq = (lane & 3) * 8;
    const ushort* sbsrc = sb_hl ? Blg : Bhg;

    auto stage = [&](int it, int db) {
        const float* ap = aBase + it * 32;
        float4 v0 = ldf4(ap), v1 = ldf4(ap + 4);
        if (FUSE) {
            const float* qp = kBase + it * 32;
            const float4 u0 = ldf4(qp), u1 = ldf4(qp + 4);
            v0.x = fmaf(cmul, u0.x, v0.x); v0.y = fmaf(cmul, u0.y, v0.y);
            v0.z = fmaf(cmul, u0.z, v0.z); v0.w = fmaf(cmul, u0.w, v0.w);
            v1.x = fmaf(cmul, u1.x, v1.x); v1.y = fmaf(cmul, u1.y, v1.y);
            v1.z = fmaf(cmul, u1.z, v1.z); v1.w = fmaf(cmul, u1.w, v1.w);
        }
        float vv[8] = {v0.x, v0.y, v0.z, v0.w, v1.x, v1.y, v1.z, v1.w};
        if (!NN) {
            #pragma unroll
            for (int j = 0; j < 8; ++j) vv[j] = cf * vv[j] * (1.f - vv[j] * vv[j]);
        }
        short8 hv, lv;
        #pragma unroll
        for (int j = 0; j < 8; ++j) {
            const ushort hb = f2bf(vv[j]);
            hv[j] = (short)hb;
            lv[j] = (short)f2bf(vv[j] - bf2f(hb));
        }
        *(short8*)&Ah[db][sa_half][sa_row][sa_kq] = hv;
        *(short8*)&Al[db][sa_half][sa_row][sa_kq] = lv;

        const size_t kb = (size_t)sb_half * 1024 + (size_t)it * 32;
        ushort* ldsB = sb_hl ? &Bl[db][sb_half][0][0] : &Bh[db][sb_half][0][0];
        const ushort* gb = sbsrc + ((size_t)col0 + sb_cl) * DDIM + kb + sb_kq;
        #pragma unroll
        for (int j = 0; j < 4; ++j)
            GLOAD_LDS16(gb + (size_t)j * 16 * DDIM, ldsB + j * 16 * 32);
    };

    f32x4 acc[2][2];
    #pragma unroll
    for (int m = 0; m < 2; ++m)
        #pragma unroll
        for (int n = 0; n < 2; ++n)
            #pragma unroll
            for (int j = 0; j < 4; ++j) acc[m][n][j] = 0.f;

    stage(0, 0);
    __syncthreads();

    // frag read: A lane(l): row=l&15 (+16*m), k=(l>>4)*8+i ; B: col=l&15, same k
    const int whalf = w >> 1, wn = w & 1;
    const int fr = lane & 15, fk = (lane >> 4) * 8;
    int db = 0;
    for (int it = 0; it < 32; ++it) {
        if (it < 31) stage(it + 1, db ^ 1);
        const short8 a0h = *(const short8*)&Ah[db][whalf][fr][fk];
        const short8 a1h = *(const short8*)&Ah[db][whalf][16 + fr][fk];
        const short8 a0l = *(const short8*)&Al[db][whalf][fr][fk];
        const short8 a1l = *(const short8*)&Al[db][whalf][16 + fr][fk];
        const short8 b0h = *(const short8*)&Bh[db][whalf][wn*32 + fr][fk];
        const short8 b1h = *(const short8*)&Bh[db][whalf][wn*32 + 16 + fr][fk];
        const short8 b0l = *(const short8*)&Bl[db][whalf][wn*32 + fr][fk];
        const short8 b1l = *(const short8*)&Bl[db][whalf][wn*32 + 16 + fr][fk];

        acc[0][0] = __builtin_amdgcn_mfma_f32_16x16x32_bf16(a0h, b0h, acc[0][0], 0, 0, 0);
        acc[0][0] = __builtin_amdgcn_mfma_f32_16x16x32_bf16(a0h, b0l, acc[0][0], 0, 0, 0);
        acc[0][0] = __builtin_amdgcn_mfma_f32_16x16x32_bf16(a0l, b0h, acc[0][0], 0, 0, 0);
        acc[0][1] = __builtin_amdgcn_mfma_f32_16x16x32_bf16(a0h, b1h, acc[0][1], 0, 0, 0);
        acc[0][1] = __builtin_amdgcn_mfma_f32_16x16x32_bf16(a0h, b1l, acc[0][1], 0, 0, 0);
        acc[0][1] = __builtin_amdgcn_mfma_f32_16x16x32_bf16(a0l, b1h, acc[0][1], 0, 0, 0);
        acc[1][0] = __builtin_amdgcn_mfma_f32_16x16x32_bf16(a1h, b0h, acc[1][0], 0, 0, 0);
        acc[1][0] = __builtin_amdgcn_mfma_f32_16x16x32_bf16(a1h, b0l, acc[1][0], 0, 0, 0);
        acc[1][0] = __builtin_amdgcn_mfma_f32_16x16x32_bf16(a1l, b0h, acc[1][0], 0, 0, 0);
        acc[1][1] = __builtin_amdgcn_mfma_f32_16x16x32_bf16(a1h, b1h, acc[1][1], 0, 0, 0);
        acc[1][1] = __builtin_amdgcn_mfma_f32_16x16x32_bf16(a1h, b1l, acc[1][1], 0, 0, 0);
        acc[1][1] = __builtin_amdgcn_mfma_f32_16x16x32_bf16(a1l, b1h, acc[1][1], 0, 0, 0);
        __syncthreads();
        db ^= 1;
    }

    // ---- K-split reduction: waves 2,3 -> waves 0,1 via LDS (reuse Ah) ----
    float* red = (float*)&Ah[0][0][0][0];   // 8 KB
    if (w >= 2) {
        float* p = red + (size_t)(w - 2) * 1024 + lane * 4;
        #pragma unroll
        for (int m = 0; m < 2; ++m)
            #pragma unroll
            for (int n = 0; n < 2; ++n)
                *(f32x4*)(p + (m*2 + n) * 256) = acc[m][n];
    }
    __syncthreads();
    if (w >= 2) return;

    {
        const float* p = red + (size_t)w * 1024 + lane * 4;
        #pragma unroll
        for (int m = 0; m < 2; ++m)
            #pragma unroll
            for (int n = 0; n < 2; ++n)
                acc[m][n] += *(const f32x4*)(p + (m*2 + n) * 256);
    }

    // ---- epilogue (waves 0,1 own 32 cols each); C/D: col=l&15, row=(l>>4)*4+j ----
    const int erow = row0 + (lane >> 4) * 4;
    const int ecol = col0 + w * 32 + fr;
    if (NN) {
        const float b0v = bias[ecol], b1v = bias[ecol + 16];
        float s2[2][4] = {{0.f,0.f,0.f,0.f},{0.f,0.f,0.f,0.f}};
        #pragma unroll
        for (int m = 0; m < 2; ++m)
            #pragma unroll
            for (int n = 0; n < 2; ++n)
                #pragma unroll
                for (int j = 0; j < 4; ++j) {
                    const float hval = tanhf(acc[m][n][j] + (n ? b1v : b0v));
                    outp[(size_t)(erow + m*16 + j) * DDIM + ecol + n*16] = hval;
                    s2[m][j] += hval * hval;
                }
        #pragma unroll
        for (int mask = 1; mask <= 8; mask <<= 1)
            #pragma unroll
            for (int m = 0; m < 2; ++m)
                #pragma unroll
                for (int j = 0; j < 4; ++j) s2[m][j] += __shfl_xor(s2[m][j], mask);
        if (fr == 0) {
            #pragma unroll
            for (int m = 0; m < 2; ++m)
                #pragma unroll
                for (int j = 0; j < 4; ++j)
                    atomicAdd(&csum_cur[erow + m*16 + j], s2[m][j]);
        }
    } else {
        float mx = 0.f;
        #pragma unroll
        for (int m = 0; m < 2; ++m)
            #pragma unroll
            for (int n = 0; n < 2; ++n)
                #pragma unroll
                for (int j = 0; j < 4; ++j) {
                    const size_t idx = (size_t)(erow + m*16 + j) * DDIM + ecol + n*16;
                    const float kv = -acc[m][n][j];
                    if (UPD) {
                        xbuf[idx] += (DT / 6.0f) * (k1p[idx] + 2.f*k2p[idx] + 2.f*k3p[idx] + kv);
                    } else {
                        outp[idx] = kv;
                        if (DOMAX) mx = fmaxf(mx, fabsf(kv));
                    }
                }
        if (DOMAX) {
            #pragma unroll
            for (int mask = 1; mask <= 32; mask <<= 1) mx = fmaxf(mx, __shfl_xor(mx, mask));
            if (lane == 0) atomicMax(maxu, __float_as_uint(mx));
        }
    }
}

__global__ void finalize_k(unsigned* __restrict__ maxu, int* __restrict__ done)
{
    if (!*done) {
        if (__uint_as_float(*maxu) < TOL) *done = 1;
    }
    *maxu = 0u;
}

__global__ __launch_bounds__(256)
void copy_k(const float* __restrict__ src, float* __restrict__ dst)
{
    const size_t i = ((size_t)blockIdx.x * 256 + threadIdx.x) * 4;
    *(float4*)&dst[i] = *(const float4*)&src[i];
}

// ===========================================================================
// LEGACY PATH (round-1 fp32 VALU pipeline) — used only if ws too small
// ===========================================================================
constexpr int LBM = 32, LBN = 64, LBK = 32;

template<bool FUSE>
__global__ __launch_bounds__(256)
void gemm_tanh_k(const float* __restrict__ xb, const float* __restrict__ kp, float c,
                 const float* __restrict__ W, const float* __restrict__ bias,
                 float* __restrict__ hout, const int* __restrict__ done)
{
    if (*done) return;
    __shared__ float As[LBK][LBM + 2];
    __shared__ float Bs[LBK][LBN + 4];
    const int t = threadIdx.x;
    const int bn = blockIdx.x, bm = blockIdx.y;
    const int row0 = bm * LBM, col0 = bn * LBN;
    const int tx = t & 15, ty = t >> 4;
    const int ar = t >> 3, ac = (t & 7) << 2;
    const int br = t >> 4, bc = (t & 15) << 2;
    const float* aPtr = xb + (size_t)(row0 + ar) * DDIM + ac;
    const float* kPtr = FUSE ? (kp + (size_t)(row0 + ar) * DDIM + ac) : nullptr;
    const float* bPtr0 = W + (size_t)br * DDIM + col0 + bc;
    const float* bPtr1 = W + (size_t)(br + 16) * DDIM + col0 + bc;
    float4 aReg, kReg, bReg0, bReg1;
    auto gload = [&](int kt) {
        aReg = *(const float4*)(aPtr + kt);
        if (FUSE) kReg = *(const float4*)(kPtr + kt);
        bReg0 = *(const float4*)(bPtr0 + (size_t)kt * DDIM);
        bReg1 = *(const float4*)(bPtr1 + (size_t)kt * DDIM);
    };
    auto sstore = [&]() {
        float4 v = aReg;
        if (FUSE) { v.x += c*kReg.x; v.y += c*kReg.y; v.z += c*kReg.z; v.w += c*kReg.w; }
        As[ac+0][ar] = v.x; As[ac+1][ar] = v.y; As[ac+2][ar] = v.z; As[ac+3][ar] = v.w;
        *(float4*)&Bs[br][bc] = bReg0;
        *(float4*)&Bs[br+16][bc] = bReg1;
    };
    float acc[2][4] = {};
    gload(0); sstore();
    for (int kt = 0; kt < DDIM; kt += LBK) {
        __syncthreads();
        const bool more = (kt + LBK) < DDIM;
        if (more) gload(kt + LBK);
        #pragma unroll
        for (int kk = 0; kk < LBK; ++kk) {
            const float2 av = *(const float2*)&As[kk][ty * 2];
            const float4 bv = *(const float4*)&Bs[kk][tx * 4];
            acc[0][0] += av.x*bv.x; acc[0][1] += av.x*bv.y; acc[0][2] += av.x*bv.z; acc[0][3] += av.x*bv.w;
            acc[1][0] += av.y*bv.x; acc[1][1] += av.y*bv.y; acc[1][2] += av.y*bv.z; acc[1][3] += av.y*bv.w;
        }
        __syncthreads();
        if (more) sstore();
    }
    const float4 bb = *(const float4*)&bias[col0 + tx * 4];
    #pragma unroll
    for (int m = 0; m < 2; ++m) {
        const int row = row0 + ty * 2 + m;
        float4 o;
        o.x = tanhf(acc[m][0] + bb.x); o.y = tanhf(acc[m][1] + bb.y);
        o.z = tanhf(acc[m][2] + bb.z); o.w = tanhf(acc[m][3] + bb.w);
        *(float4*)&hout[(size_t)row * DDIM + col0 + tx * 4] = o;
    }
}

template<bool DOMAXL>
__global__ __launch_bounds__(256)
void gemm_nt_k(const float* __restrict__ h, const float* __restrict__ coef,
               const float* __restrict__ W, float* __restrict__ kout,
               unsigned* __restrict__ maxu, const int* __restrict__ done)
{
    if (*done) return;
    __shared__ float As[LBK][LBM + 2];
    __shared__ float Bs[LBK][LBN + 4];
    const int t = threadIdx.x;
    const int bn = blockIdx.x, bm = blockIdx.y;
    const int row0 = bm * LBM, col0 = bn * LBN;
    const int tx = t & 15, ty = t >> 4;
    const int ar = t >> 3, ac = (t & 7) << 2;
    const int bj = t >> 3, bk = (t & 7) << 2;
    const float cfv = coef[row0 + ar];
    const float* aPtr = h + (size_t)(row0 + ar) * DDIM + ac;
    const float* bPtr0 = W + (size_t)(col0 + bj) * DDIM + bk;
    const float* bPtr1 = W + (size_t)(col0 + bj + 32) * DDIM + bk;
    float4 aReg, bReg0, bReg1;
    auto gload = [&](int kt) {
        aReg = *(const float4*)(aPtr + kt);
        bReg0 = *(const float4*)(bPtr0 + kt);
        bReg1 = *(const float4*)(bPtr1 + kt);
    };
    auto sstore = [&]() {
        const float g0 = cfv*aReg.x*(1.f-aReg.x*aReg.x);
        const float g1 = cfv*aReg.y*(1.f-aReg.y*aReg.y);
        const float g2 = cfv*aReg.z*(1.f-aReg.z*aReg.z);
        const float g3 = cfv*aReg.w*(1.f-aReg.w*aReg.w);
        As[ac+0][ar] = g0; As[ac+1][ar] = g1; As[ac+2][ar] = g2; As[ac+3][ar] = g3;
        Bs[bk+0][bj] = bReg0.x; Bs[bk+1][bj] = bReg0.y; Bs[bk+2][bj] = bReg0.z; Bs[bk+3][bj] = bReg0.w;
        Bs[bk+0][bj+32] = bReg1.x; Bs[bk+1][bj+32] = bReg1.y; Bs[bk+2][bj+32] = bReg1.z; Bs[bk+3][bj+32] = bReg1.w;
    };
    float acc[2][4] = {};
    gload(0); sstore();
    for (int kt = 0; kt < DDIM; kt += LBK) {
        __syncthreads();
        const bool more = (kt + LBK) < DDIM;
        if (more) gload(kt + LBK);
        #pragma unroll
        for (int kk = 0; kk < LBK; ++kk) {
            const float2 av = *(const float2*)&As[kk][ty * 2];
            const float4 bv = *(const float4*)&Bs[kk][tx * 4];
            acc[0][0] += av.x*bv.x; acc[0][1] += av.x*bv.y; acc[0][2] += av.x*bv.z; acc[0][3] += av.x*bv.w;
            acc[1][0] += av.y*bv.x; acc[1][1] += av.y*bv.y; acc[1][2] += av.y*bv.z; acc[1][3] += av.y*bv.w;
        }
        __syncthreads();
        if (more) sstore();
    }
    float mx = 0.f;
    #pragma unroll
    for (int m = 0; m < 2; ++m) {
        const int row = row0 + ty * 2 + m;
        float4 o;
        o.x = -acc[m][0]; o.y = -acc[m][1]; o.z = -acc[m][2]; o.w = -acc[m][3];
        *(float4*)&kout[(size_t)row * DDIM + col0 + tx * 4] = o;
        if (DOMAXL)
            mx = fmaxf(mx, fmaxf(fmaxf(fabsf(o.x), fabsf(o.y)), fmaxf(fabsf(o.z), fabsf(o.w))));
    }
    if (DOMAXL) {
        #pragma unroll
        for (int off = 32; off; off >>= 1) mx = fmaxf(mx, __shfl_xor(mx, off));
        if ((t & 63) == 0) atomicMax(maxu, __float_as_uint(mx));
    }
}

__global__ __launch_bounds__(256)
void rowcoef_k(const float* __restrict__ h, float* __restrict__ coef,
               const int* __restrict__ done)
{
    if (*done) return;
    const int r = blockIdx.x;
    const float* p = h + (size_t)r * DDIM;
    float s = 0.f;
    for (int j = threadIdx.x * 4; j < DDIM; j += 256 * 4) {
        const float4 v = *(const float4*)&p[j];
        s += v.x*v.x + v.y*v.y + v.z*v.z + v.w*v.w;
    }
    #pragma unroll
    for (int off = 32; off; off >>= 1) s += __shfl_xor(s, off);
    __shared__ float wsum[4];
    if ((threadIdx.x & 63) == 0) wsum[threadIdx.x >> 6] = s;
    __syncthreads();
    if (threadIdx.x == 0) coef[r] = 5.0f / (sqrtf(wsum[0]+wsum[1]+wsum[2]+wsum[3]) + EPS_);
}

__global__ __launch_bounds__(256)
void update_k(float* __restrict__ x, const float* __restrict__ k1,
              const float* __restrict__ k2, const float* __restrict__ k3,
              const float* __restrict__ k4, const int* __restrict__ done)
{
    if (*done) return;
    const size_t i = ((size_t)blockIdx.x * 256 + threadIdx.x) * 4;
    float4 xv = *(const float4*)&x[i];
    const float4 a = *(const float4*)&k1[i];
    const float4 b = *(const float4*)&k2[i];
    const float4 c = *(const float4*)&k3[i];
    const float4 d = *(const float4*)&k4[i];
    const float s = DT / 6.0f;
    xv.x += s*(a.x + 2.f*b.x + 2.f*c.x + d.x);
    xv.y += s*(a.y + 2.f*b.y + 2.f*c.y + d.y);
    xv.z += s*(a.z + 2.f*b.z + 2.f*c.z + d.z);
    xv.w += s*(a.w + 2.f*b.w + 2.f*c.w + d.w);
    *(float4*)&x[i] = xv;
}

__global__ __launch_bounds__(256)
void init_k(const float* __restrict__ x0, float* __restrict__ x,
            unsigned* __restrict__ maxu, int* __restrict__ done)
{
    const size_t i = ((size_t)blockIdx.x * 256 + threadIdx.x) * 4;
    *(float4*)&x[i] = *(const float4*)&x0[i];
    if (blockIdx.x == 0 && threadIdx.x == 0) { *maxu = 0u; *done = 0; }
}

// ===========================================================================
extern "C" void kernel_launch(void* const* d_in, const int* in_sizes, int n_in,
                              void* d_out, int out_size, void* d_ws, size_t ws_size,
                              hipStream_t stream)
{
    const float* x0   = (const float*)d_in[0];
    const float* W    = (const float*)d_in[1];
    const float* bias = (const float*)d_in[2];
    float* out = (float*)d_out;

    const size_t NE = (size_t)BDIM * DDIM;       // 524288
    const size_t M4 = (size_t)DDIM * DDIM;       // 4194304
    const size_t need = (5*NE + 2048) * 4 + 4 * M4 * 2;   // ~44.0 MB

    const int gE = (int)(NE / 1024);             // 512 elementwise blocks

    if (ws_size >= need) {
        // -------- new MFMA path --------
        float* ws = (float*)d_ws;
        float* x  = ws;
        float* h  = ws + NE;
        float* k1 = ws + 2*NE;
        float* k2 = ws + 3*NE;
        float* k3 = ws + 4*NE;
        float* csum = ws + 5*NE;                 // 4 stage buffers x 256
        unsigned* maxu = (unsigned*)(csum + 1024);
        int* done = (int*)(maxu + 1);
        ushort* us  = (ushort*)(ws + 5*NE + 2048);
        ushort* Wth = us;            // W^T hi  (NN B operand)
        ushort* Wtl = us + M4;       // W^T lo
        ushort* Wh  = us + 2*M4;     // W hi    (NT B operand)
        ushort* Wl  = us + 3*M4;     // W lo

        prep_w_k <<<4096, 256, 0, stream>>>(W, Wh, Wl);
        prep_wt_k<<<dim3(32, 32), 256, 0, stream>>>(W, Wth, Wtl);
        init2_k  <<<gE, 256, 0, stream>>>(x0, x, csum, maxu, done);

        const dim3 gG(DDIM / 64, BDIM / 32);     // (32, 8)
        float* cs0 = csum, *cs1 = csum + 256, *cs2 = csum + 512, *cs3 = csum + 768;

        for (int s = 0; s < NSTEP; ++s) {
            // k1 = pvf(x); feeds stop condition
            hop_mm<0><<<gG,256,0,stream>>>(x, nullptr, 0.f, Wth, Wtl, bias, h,
                                           cs0, nullptr, nullptr,nullptr,nullptr,nullptr, nullptr, done);
            hop_mm<3><<<gG,256,0,stream>>>(h, nullptr, 0.f, Wh, Wl, bias, k1,
                                           cs0, cs1, nullptr,nullptr,nullptr,nullptr, maxu, done);
            finalize_k<<<1,1,0,stream>>>(maxu, done);
            // k2 = pvf(x + 0.5*DT*k1)
            hop_mm<1><<<gG,256,0,stream>>>(x, k1, 0.5f*DT, Wth, Wtl, bias, h,
                                           cs1, nullptr, nullptr,nullptr,nullptr,nullptr, nullptr, done);
            hop_mm<2><<<gG,256,0,stream>>>(h, nullptr, 0.f, Wh, Wl, bias, k2,
                                           cs1, cs2, nullptr,nullptr,nullptr,nullptr, nullptr, done);
            // k3 = pvf(x + 0.5*DT*k2)
            hop_mm<1><<<gG,256,0,stream>>>(x, k2, 0.5f*DT, Wth, Wtl, bias, h,
                                           cs2, nullptr, nullptr,nullptr,nullptr,nullptr, nullptr, done);
            hop_mm<2><<<gG,256,0,stream>>>(h, nullptr, 0.f, Wh, Wl, bias, k3,
                                           cs2, cs3, nullptr,nullptr,nullptr,nullptr, nullptr, done);
            // k4 = pvf(x + DT*k3); x-update fused into epilogue
            hop_mm<1><<<gG,256,0,stream>>>(x, k3, DT, Wth, Wtl, bias, h,
                                           cs3, nullptr, nullptr,nullptr,nullptr,nullptr, nullptr, done);
            hop_mm<4><<<gG,256,0,stream>>>(h, nullptr, 0.f, Wh, Wl, bias, h,
                                           cs3, cs0, k1, k2, k3, x, nullptr, done);
        }
        copy_k<<<gE, 256, 0, stream>>>(x, out);
    } else {
        // -------- legacy fp32 path (round-1, known-good) --------
        float* ws = (float*)d_ws;
        float* x    = ws;
        float* h    = ws + NE;
        float* k1   = ws + 2*NE;
        float* k2   = ws + 3*NE;
        float* k3   = ws + 4*NE;
        float* k4   = ws + 5*NE;
        float* coef = ws + 6*NE;
        unsigned* maxu = (unsigned*)(ws + 6*NE + BDIM);
        int* done = (int*)(ws + 6*NE + BDIM + 1);

        const dim3 gG(DDIM / LBN, BDIM / LBM);
        init_k<<<gE, 256, 0, stream>>>(x0, x, maxu, done);
        for (int s = 0; s < NSTEP; ++s) {
            gemm_tanh_k<false><<<gG,256,0,stream>>>(x, nullptr, 0.f, W, bias, h, done);
            rowcoef_k<<<BDIM,256,0,stream>>>(h, coef, done);
            gemm_nt_k<true><<<gG,256,0,stream>>>(h, coef, W, k1, maxu, done);
            finalize_k<<<1,1,0,stream>>>(maxu, done);
            gemm_tanh_k<true><<<gG,256,0,stream>>>(x, k1, 0.5f*DT, W, bias, h, done);
            rowcoef_k<<<BDIM,256,0,stream>>>(h, coef, done);
            gemm_nt_k<false><<<gG,256,0,stream>>>(h, coef, W, k2, nullptr, done);
            gemm_tanh_k<true><<<gG,256,0,stream>>>(x, k2, 0.5f*DT, W, bias, h, done);
            rowcoef_k<<<BDIM,256,0,stream>>>(h, coef, done);
            gemm_nt_k<false><<<gG,256,0,stream>>>(h, coef, W, k3, nullptr, done);
            gemm_tanh_k<true><<<gG,256,0,stream>>>(x, k3, DT, W, bias, h, done);
            rowcoef_k<<<BDIM,256,0,stream>>>(h, coef, done);
            gemm_nt_k<false><<<gG,256,0,stream>>>(h, coef, W, k4, nullptr, done);
            update_k<<<gE,256,0,stream>>>(x, k1, k2, k3, k4, done);
        }
        copy_k<<<gE, 256, 0, stream>>>(x, out);
    }
}